// Round 1
// baseline (418.968 us; speedup 1.0000x reference)
//
#include <hip/hip_runtime.h>
#include <stdint.h>

// Problem constants
#define ZSIZE   8388608      // 32*256*32*32
#define NPIX    32768        // 32*32*32
#define IDX_OFF ZSIZE        // idx output offset (floats) in d_out
#define LOSS_OFF (ZSIZE + NPIX)
#define ET_OFF  1024         // Et scratch offset (words) in d_out[0..ZSIZE) region
                             // d_out[0..1024) = se scratch; both overwritten by kout later.

// ---------------------------------------------------------------------------
// ktr: transpose embedding E[1024][256] -> Et[256][1024] stored in d_out scratch
// ---------------------------------------------------------------------------
__global__ __launch_bounds__(256) void ktr(const float* __restrict__ E,
                                           float* __restrict__ out) {
  __shared__ float tile[64][65];                 // +1 pad breaks bank conflicts
  const int k0 = blockIdx.x * 64;                // 16 blocks in x
  const int c0 = blockIdx.y * 64;                // 4 blocks in y
  const int t = threadIdx.x;
  #pragma unroll
  for (int i = 0; i < 4; i++) {
    int f = t + 256 * i;                         // 0..1023
    int r = f >> 4, q = f & 15;
    float4 e = *(const float4*)(E + (k0 + r) * 256 + c0 + 4 * q);
    tile[r][4 * q + 0] = e.x; tile[r][4 * q + 1] = e.y;
    tile[r][4 * q + 2] = e.z; tile[r][4 * q + 3] = e.w;
  }
  __syncthreads();
  #pragma unroll
  for (int i = 0; i < 4; i++) {
    int f = t + 256 * i;
    int cr = f >> 4, kq = f & 15;
    float4 o;
    o.x = tile[4 * kq + 0][cr];
    o.y = tile[4 * kq + 1][cr];
    o.z = tile[4 * kq + 2][cr];
    o.w = tile[4 * kq + 3][cr];
    *(float4*)(out + ET_OFF + (c0 + cr) * 1024 + k0 + 4 * kq) = o;
  }
}

// ---------------------------------------------------------------------------
// kse: se[k] = sum_c E[k][c]^2  (order-insensitive at this magnitude; coalesced
// reads from Et). Written to d_out[0..1024).
// ---------------------------------------------------------------------------
__global__ __launch_bounds__(256) void kse(float* __restrict__ out) {
  const int k = blockIdx.x * 256 + threadIdx.x;  // 4 blocks
  const float* Et = out + ET_OFF;
  float acc = 0.0f;
  for (int c = 0; c < 256; c++) {
    float v = Et[c * 1024 + k];
    acc = __fadd_rn(acc, __fmul_rn(v, v));
  }
  out[k] = acc;
}

// ---------------------------------------------------------------------------
// kmain: fused distance GEMM + argmin.
// Block = (ccg, b): 16 channel-rows (cc0..cc0+15) x 4 w-offsets = 64 pixels.
// V-tile resident in LDS (64KB). Codes iterated in 8 tiles of 128, c staged
// in chunks of 16. Micro-tile 4 pixels x 8 codes per thread (16x16 grid).
// dist replicates reference fp32 rounding: fl(fl(se+sz) - 2*dot), argmin with
// first-index tie-break.
// ---------------------------------------------------------------------------
__global__ __launch_bounds__(256, 2) void kmain(const float* __restrict__ z,
                                                float* __restrict__ out) {
  __shared__ float Vs[16 * 1024];   // 64 KB: raw copy of 16 channel rows
  __shared__ float Es[16 * 128];    // 8 KB: E chunk, [c][code]; reused as red-dist
  __shared__ float Ri[16 * 64];     // idx reduction buffer (1KB... actually 4KB)
  __shared__ float szs[64];

  const int t = threadIdx.x;
  const int ccg = blockIdx.x;       // 0..15
  const int b = blockIdx.y;         // 0..31
  const int cc0 = ccg * 16;
  const float* zb = z + (size_t)b * 262144;
  const float* se_g = out;
  const float* Et_g = out + ET_OFF;

  // one thread in the whole grid zeroes the loss accumulator (kout runs after)
  if (ccg == 0 && b == 0 && t == 0) out[LOSS_OFF] = 0.0f;

  // ---- stage V-tile: 16 contiguous rows of 1024 floats ----
  #pragma unroll
  for (int i = 0; i < 16; i++) {
    int f = t + 256 * i;            // 0..4095 float4s
    int r = f >> 8, q = f & 255;
    float4 v = *(const float4*)(zb + (cc0 + r) * 1024 + 4 * q);
    *(float4*)(Vs + r * 1024 + 4 * q) = v;
  }
  __syncthreads();

  // ---- sz per pixel: np-faithful sequential ascending-c, mul then add ----
  if (t < 64) {
    int r = t >> 2, w0 = t & 3;
    float acc = 0.0f;
    for (int c = 0; c < 256; c++) {
      float v = Vs[r * 1024 + 4 * c + w0];
      acc = __fadd_rn(acc, __fmul_rn(v, v));
    }
    szs[t] = acc;                   // pixel p = t = r*4 + w0
  }
  // (covered by the first barrier inside the chunk loop)

  const int ty = t >> 4;            // pixel group (channel row), 0..15
  const int tx = t & 15;            // code group, 0..15

  float bestd[4];
  int besti[4];
  #pragma unroll
  for (int i = 0; i < 4; i++) { bestd[i] = 3.4e38f; besti[i] = 0; }

  for (int kt = 0; kt < 8; kt++) {
    const int k0 = kt * 128;
    float acc[4][8];
    #pragma unroll
    for (int i = 0; i < 4; i++)
      #pragma unroll
      for (int j = 0; j < 8; j++) acc[i][j] = 0.0f;

    for (int ci = 0; ci < 16; ci++) {
      const int c0 = ci * 16;
      __syncthreads();              // protect Es readers of previous chunk
      // stage Es[16][128] from Et
      #pragma unroll
      for (int i = 0; i < 2; i++) {
        int f = t + 256 * i;        // 0..511 float4s
        int r = f >> 5, q = f & 31;
        float4 e = *(const float4*)(Et_g + (c0 + r) * 1024 + k0 + 4 * q);
        *(float4*)(Es + r * 128 + 4 * q) = e;
      }
      __syncthreads();

      #pragma unroll
      for (int c = 0; c < 16; c++) {
        float4 v = *(const float4*)(Vs + ty * 1024 + 4 * (c0 + c));
        float4 ea = *(const float4*)(Es + c * 128 + 4 * tx);
        float4 eb = *(const float4*)(Es + c * 128 + 64 + 4 * tx);
        float vv[4] = {v.x, v.y, v.z, v.w};
        float ee[8] = {ea.x, ea.y, ea.z, ea.w, eb.x, eb.y, eb.z, eb.w};
        #pragma unroll
        for (int i = 0; i < 4; i++)
          #pragma unroll
          for (int j = 0; j < 8; j++)
            acc[i][j] = __fmaf_rn(vv[i], ee[j], acc[i][j]);
      }
    }

    // ---- epilogue: dist + running argmin (codes strictly ascending) ----
    float4 sa = *(const float4*)(se_g + k0 + 4 * tx);
    float4 sb = *(const float4*)(se_g + k0 + 64 + 4 * tx);
    float se8[8] = {sa.x, sa.y, sa.z, sa.w, sb.x, sb.y, sb.z, sb.w};
    #pragma unroll
    for (int i = 0; i < 4; i++) {
      float sz = szs[4 * ty + i];
      #pragma unroll
      for (int j = 0; j < 8; j++) {
        int code = k0 + 4 * tx + ((j < 4) ? j : (64 + (j - 4)));
        // reference: dist = fl(fl(se + sz) - 2*dot); 2*dot is exact
        float d = __fsub_rn(__fadd_rn(se8[j], sz), __fmul_rn(2.0f, acc[i][j]));
        if (d < bestd[i]) { bestd[i] = d; besti[i] = code; }  // strict < = first idx
      }
    }
  }

  // ---- cross-thread reduction over the 16 code groups ----
  __syncthreads();                  // Es dead; reuse as dist buffer
  #pragma unroll
  for (int i = 0; i < 4; i++) {
    Es[tx * 64 + ty * 4 + i] = bestd[i];
    Ri[tx * 64 + ty * 4 + i] = (float)besti[i];
  }
  __syncthreads();
  if (t < 64) {
    float bd = Es[t];
    int bi = (int)Ri[t];
    #pragma unroll
    for (int x = 1; x < 16; x++) {
      float d = Es[x * 64 + t];
      int i2 = (int)Ri[x * 64 + t];
      if (d < bd || (d == bd && i2 < bi)) { bd = d; bi = i2; }  // tie -> lower k
    }
    int r = t >> 2, w0 = t & 3;
    int n = w0 * 256 + cc0 + r;     // n = hh*32 + ww
    out[IDX_OFF + b * 1024 + n] = (float)bi;
  }
}

// ---------------------------------------------------------------------------
// kout: z_q_st = fl(zp + fl(zq - zp)), loss partial sums
// ---------------------------------------------------------------------------
__global__ __launch_bounds__(256) void kout(const float* __restrict__ z,
                                            const float* __restrict__ E,
                                            float* __restrict__ out) {
  __shared__ float red[4];
  const int t = threadIdx.x;
  const size_t g4 = (size_t)blockIdx.x * 256 + t;
  const size_t g = g4 * 4;                       // word index into z / out0
  const int b = (int)(g >> 18);
  const int c = (int)((g >> 10) & 255);
  const int n = (int)(g & 1023);

  float4 zp = *(const float4*)(z + g);
  float4 idxf = *(const float4*)(out + IDX_OFF + b * 1024 + n);
  int i0 = (int)idxf.x, i1 = (int)idxf.y, i2 = (int)idxf.z, i3 = (int)idxf.w;
  float q0 = E[i0 * 256 + c];
  float q1 = E[i1 * 256 + c];
  float q2 = E[i2 * 256 + c];
  float q3 = E[i3 * 256 + c];
  float d0 = __fsub_rn(q0, zp.x);
  float d1 = __fsub_rn(q1, zp.y);
  float d2 = __fsub_rn(q2, zp.z);
  float d3 = __fsub_rn(q3, zp.w);
  float4 o;
  o.x = __fadd_rn(zp.x, d0);
  o.y = __fadd_rn(zp.y, d1);
  o.z = __fadd_rn(zp.z, d2);
  o.w = __fadd_rn(zp.w, d3);
  *(float4*)(out + g) = o;

  float s = d0 * d0 + d1 * d1 + d2 * d2 + d3 * d3;
  #pragma unroll
  for (int off = 32; off > 0; off >>= 1) s += __shfl_down(s, off);
  if ((t & 63) == 0) red[t >> 6] = s;
  __syncthreads();
  if (t == 0) {
    float bs = red[0] + red[1] + red[2] + red[3];
    atomicAdd(out + LOSS_OFF, bs);
  }
}

// ---------------------------------------------------------------------------
// kfin: loss = m + 0.25*m, m = S / N
// ---------------------------------------------------------------------------
__global__ void kfin(float* __restrict__ out) {
  if (threadIdx.x == 0) {
    float S = out[LOSS_OFF];
    float m = S / 8388608.0f;
    out[LOSS_OFF] = __fadd_rn(m, __fmul_rn(0.25f, m));
  }
}

extern "C" void kernel_launch(void* const* d_in, const int* in_sizes, int n_in,
                              void* d_out, int out_size, void* d_ws, size_t ws_size,
                              hipStream_t stream) {
  const float* z = (const float*)d_in[0];    // [32,256,32,32]
  const float* E = (const float*)d_in[1];    // [1024,256]
  float* out = (float*)d_out;

  ktr<<<dim3(16, 4), 256, 0, stream>>>(E, out);
  kse<<<dim3(4), 256, 0, stream>>>(out);
  kmain<<<dim3(16, 32), 256, 0, stream>>>(z, out);
  kout<<<dim3(8192), 256, 0, stream>>>(z, E, out);
  kfin<<<dim3(1), 64, 0, stream>>>(out);
}